// Round 1
// baseline (185.345 us; speedup 1.0000x reference)
//
#include <hip/hip_runtime.h>

// Varifold loss, round 13: 1 i-tile per wave (32 rows) with cross-iteration
// MFMA skew — chunk k+1's T/D MFMAs issue during chunk k's epilogue
// (depth-2 B prefetch), removing the MFMA-latency stall that phase-locked
// waves in the 2-tile version. Batched-sign accumulation: 4 packed f32x2
// accumulator chains, sign flipped ONCE at the mesh-boundary crossing kc
// instead of per-iteration cndmask+fold. k=0 (diagonal weight) and the
// final iteration are peeled; SPLITS 26->13 doubles k-loop length to
// amortize per-panel prologue. Panels of 128 rows, balanced pairing.
//
// t_ij = cq_i + cq_j + TG*<C_i,C_j>;  d_ij = <m_i,m_j>;  term = exp2(t)*d^2.

#define NVERT 5023
#define NFACE 9976
#define BATCH 4
#define HALFP 9984             // per-mesh faces padded: 78 panels x 128
#define NTP   (2 * HALFP)      // 19968 faces per batch
#define NTOT  (BATCH * NTP)    // 79872
#define NCH   624              // j-chunks of 32 per batch
#define NPAN  156              // i-panels of 128 rows
#define SPLITS 13

constexpr float GAMMA = 1.0f / (0.03f * 0.03f);
constexpr float LOG2E = 1.4426950408889634f;
constexpr float EPSV  = 1e-12f;

typedef _Float16 half8_t  __attribute__((ext_vector_type(8)));
typedef float    f32x16   __attribute__((ext_vector_type(16)));
typedef float    f32x2    __attribute__((ext_vector_type(2)));

__global__ __launch_bounds__(256)
void face_quant_kernel(const float* __restrict__ pred,
                       const float* __restrict__ targ,
                       const int*   __restrict__ faces,
                       _Float16*    __restrict__ fd,
                       float*       __restrict__ out) {
    int idx = blockIdx.x * 256 + threadIdx.x;
    if (idx == 0) out[0] = 0.0f;
    if (idx >= NTOT) return;

    int b     = idx / NTP;
    int s     = idx - b * NTP;
    int which = (s >= HALFP) ? 1 : 0;
    int f     = s - which * HALFP;

    _Float16* arec = fd + (size_t)idx * 32;
    _Float16* brec = fd + (size_t)NTOT * 32 + (size_t)idx * 32;

    if (f >= NFACE) {
        half8_t z = {};
        *(half8_t*)(arec + 0) = z; *(half8_t*)(arec + 8)  = z;
        *(half8_t*)(arec + 16) = z; *(half8_t*)(arec + 24) = z;
        *(half8_t*)(brec + 0) = z; *(half8_t*)(brec + 8)  = z;
        *(half8_t*)(brec + 16) = z; *(half8_t*)(brec + 24) = z;
        return;
    }

    const float* V = (which ? targ : pred) + (size_t)b * NVERT * 3;
    int i0 = faces[f * 3 + 0];
    int i1 = faces[f * 3 + 1];
    int i2 = faces[f * 3 + 2];

    float v0x = V[i0*3+0], v0y = V[i0*3+1], v0z = V[i0*3+2];
    float v1x = V[i1*3+0], v1y = V[i1*3+1], v1z = V[i1*3+2];
    float v2x = V[i2*3+0], v2y = V[i2*3+1], v2z = V[i2*3+2];

    const float third = 1.0f / 3.0f;
    float cx = (v0x + v1x + v2x) * third;
    float cy = (v0y + v1y + v2y) * third;
    float cz = (v0z + v1z + v2z) * third;

    float e1x = v1x - v0x, e1y = v1y - v0y, e1z = v1z - v0z;
    float e2x = v2x - v0x, e2y = v2y - v0y, e2z = v2z - v0z;

    float nx = 0.5f * (e1y * e2z - e1z * e2y);
    float ny = 0.5f * (e1z * e2x - e1x * e2z);
    float nz = 0.5f * (e1x * e2y - e1y * e2x);

    float L   = sqrtf(nx*nx + ny*ny + nz*nz);
    float inv = 1.0f / fmaxf(L, EPSV);
    float sc  = inv * sqrtf(L);            // m = Nn*sqrt(L)
    float mx = nx * sc, my = ny * sc, mz = nz * sc;

    const float TG = 2.0f * GAMMA * LOG2E;
    float tgx = TG * cx, tgy = TG * cy, tgz = TG * cz;
    float cq  = -GAMMA * LOG2E * (cx*cx + cy*cy + cz*cz);

    _Float16 TGxh = (_Float16)tgx; _Float16 TGxl = (_Float16)(tgx - (float)TGxh);
    _Float16 TGyh = (_Float16)tgy; _Float16 TGyl = (_Float16)(tgy - (float)TGyh);
    _Float16 TGzh = (_Float16)tgz; _Float16 TGzl = (_Float16)(tgz - (float)TGzh);
    _Float16 Cxh  = (_Float16)cx;  _Float16 Cxl  = (_Float16)(cx  - (float)Cxh);
    _Float16 Cyh  = (_Float16)cy;  _Float16 Cyl  = (_Float16)(cy  - (float)Cyh);
    _Float16 Czh  = (_Float16)cz;  _Float16 Czl  = (_Float16)(cz  - (float)Czh);
    _Float16 cqh  = (_Float16)cq;  _Float16 cql  = (_Float16)(cq  - (float)cqh);
    _Float16 mxh  = (_Float16)mx;  _Float16 mxl  = (_Float16)(mx  - (float)mxh);
    _Float16 myh  = (_Float16)my;  _Float16 myl  = (_Float16)(my  - (float)myh);
    _Float16 mzh  = (_Float16)mz;  _Float16 mzl  = (_Float16)(mz  - (float)mzh);
    _Float16 one  = (_Float16)1.0f;
    _Float16 zz   = (_Float16)0.0f;

    half8_t ta0 = {TGxh, TGyh, TGzh, TGxl, TGyl, TGzl, TGxh, TGyh};
    half8_t ta1 = {TGzh, TGxl, TGyl, TGzl, cqh,  cql,  one,  one };
    half8_t da0 = {mxh,  myh,  mzh,  mxl,  myl,  mzl,  mxh,  myh };
    half8_t da1 = {mzh,  mxl,  myl,  mzl,  zz,   zz,   zz,   zz  };
    half8_t tb0 = {Cxh,  Cyh,  Czh,  Cxh,  Cyh,  Czh,  Cxl,  Cyl };
    half8_t tb1 = {Czl,  Cxl,  Cyl,  Czl,  one,  one,  cqh,  cql };
    half8_t db0 = {mxh,  myh,  mzh,  mxh,  myh,  mzh,  mxl,  myl };
    half8_t db1 = {mzl,  mxl,  myl,  mzl,  zz,   zz,   zz,   zz  };

    *(half8_t*)(arec + 0)  = ta0;  *(half8_t*)(arec + 8)  = ta1;
    *(half8_t*)(arec + 16) = da0;  *(half8_t*)(arec + 24) = da1;
    *(half8_t*)(brec + 0)  = tb0;  *(half8_t*)(brec + 8)  = tb1;
    *(half8_t*)(brec + 16) = db0;  *(half8_t*)(brec + 24) = db1;
}

__device__ __forceinline__ half8_t ld8(const _Float16* p) {
    return *(const half8_t*)p;
}

// Epilogue: term = exp2(T)*D^2, accumulated into 4 rotating packed chains.
// All aa indices are compile-time constants after full unroll.
#define EPI(T_, D_)                                                       \
    {                                                                     \
        _Pragma("unroll")                                                 \
        for (int r = 0; r < 16; r += 2) {                                 \
            f32x2 e_ = {__builtin_amdgcn_exp2f((T_)[r]),                  \
                        __builtin_amdgcn_exp2f((T_)[r + 1])};             \
            f32x2 d_ = {(D_)[r], (D_)[r + 1]};                            \
            d_ = d_ * d_;                                                 \
            aa[(r >> 1) & 3] = e_ * d_ + aa[(r >> 1) & 3];                \
        }                                                                 \
    }

__global__ __launch_bounds__(256, 4)
void pair_sum_kernel(const _Float16* __restrict__ fd,
                     float*          __restrict__ out) {
    const int b       = blockIdx.z;
    const int pairIdx = blockIdx.x / SPLITS;     // 0..77
    const int s       = blockIdx.x % SPLITS;

    const _Float16* Arec = fd;
    const _Float16* Brec = fd + (size_t)NTOT * 32;

    const int lane = threadIdx.x & 63;
    const int w    = threadIdx.x >> 6;
    const int col  = lane & 31;
    const int koff = (lane >> 5) * 8;

    const size_t bface = (size_t)b * NTP;
    const size_t JSTEP = (size_t)SPLITS * 32 * 32;

    float acc = 0.0f;
    const f32x16 z   = {};
    const f32x2  z2  = {};

    #pragma unroll 1
    for (int h = 0; h < 2; ++h) {
        const int   P  = h ? (NPAN - 1 - pairIdx) : pairIdx;
        const int   c0 = 4 * P;
        const float si = (P < NPAN / 2) ? 1.0f : -1.0f;
        const int   iters = (NCH - c0 - s + SPLITS - 1) / SPLITS;
        if (iters <= 0) continue;

        // this wave's 32 i-rows
        const _Float16* ap = Arec + (bface + (size_t)(P * 128 + w * 32 + col)) * 32 + koff;
        half8_t aT = ld8(ap);
        half8_t aD = ld8(ap + 16);

        const _Float16* pB = Brec + (bface + (size_t)((c0 + s) * 32 + col)) * 32 + koff;
        half8_t cT = ld8(pB), cD = ld8(pB + 16);

        // sign crossing: j-chunks < NCH/2 are mesh0 (sj=si), >= are mesh1 (sj=-si)
        const int   rem   = NCH / 2 - (c0 + s);
        const int   kc    = (rem > 0) ? ((rem + SPLITS - 1) / SPLITS) : 0;
        const int   ktrig = (kc > 1 && kc < iters) ? kc : -1;
        const float sgn2  = ((kc >= iters) ? si : -si) * 2.0f;

        f32x2 aa[4] = {};

        // ---- peel k = 0 (diagonal chunk: weight 1 when s < 4) ----
        f32x16 T = __builtin_amdgcn_mfma_f32_32x32x16_f16(aT, cT, z, 0, 0, 0);
        f32x16 D = __builtin_amdgcn_mfma_f32_32x32x16_f16(aD, cD, z, 0, 0, 0);
        half8_t nT = cT, nD = cD;
        if (iters > 1) { pB += JSTEP; nT = ld8(pB); nD = ld8(pB + 16); }   // chunk 1
        EPI(T, D);
        {
            f32x2 A2 = (aa[0] + aa[1]) + (aa[2] + aa[3]);
            const float sj0 = (rem > 0) ? si : -si;
            const float wg  = (s < 4) ? 1.0f : 2.0f;
            acc = fmaf(sj0 * wg, A2.x + A2.y, acc);
            aa[0] = z2; aa[1] = z2; aa[2] = z2; aa[3] = z2;
        }

        // ---- skewed main pipeline: chunk k+1's MFMAs issue during chunk k's
        //      epilogue; B loads run two chunks ahead ----
        if (iters > 1) {
            T = __builtin_amdgcn_mfma_f32_32x32x16_f16(aT, nT, z, 0, 0, 0);  // chunk 1
            D = __builtin_amdgcn_mfma_f32_32x32x16_f16(aD, nD, z, 0, 0, 0);
            if (iters > 2) { pB += JSTEP; nT = ld8(pB); nD = ld8(pB + 16); } // chunk 2

            #pragma unroll 2
            for (int k = 1; k <= iters - 2; ++k) {
                // issue chunk k+1 (operands loaded one body ago)
                f32x16 Tn = __builtin_amdgcn_mfma_f32_32x32x16_f16(aT, nT, z, 0, 0, 0);
                f32x16 Dn = __builtin_amdgcn_mfma_f32_32x32x16_f16(aD, nD, z, 0, 0, 0);
                // prefetch chunk k+2 (exists iff k+3 <= iters)
                if (k + 3 <= iters) { pB += JSTEP; nT = ld8(pB); nD = ld8(pB + 16); }
                if (k == ktrig) { aa[0] = -aa[0]; aa[1] = -aa[1]; aa[2] = -aa[2]; aa[3] = -aa[3]; }
                EPI(T, D);            // chunk k (MFMA issued one body ago)
                T = Tn; D = Dn;
            }
            if (iters - 1 == ktrig) { aa[0] = -aa[0]; aa[1] = -aa[1]; aa[2] = -aa[2]; aa[3] = -aa[3]; }
            EPI(T, D);                // chunk iters-1
        }

        f32x2 A2 = (aa[0] + aa[1]) + (aa[2] + aa[3]);
        acc = fmaf(sgn2, A2.x + A2.y, acc);
    }

    acc *= (1.0f / BATCH);

    #pragma unroll
    for (int off = 32; off > 0; off >>= 1)
        acc += __shfl_down(acc, off, 64);

    __shared__ float wsum[4];
    if (lane == 0) wsum[w] = acc;
    __syncthreads();
    if (threadIdx.x == 0)
        atomicAdd(out, wsum[0] + wsum[1] + wsum[2] + wsum[3]);
}

extern "C" void kernel_launch(void* const* d_in, const int* in_sizes, int n_in,
                              void* d_out, int out_size, void* d_ws, size_t ws_size,
                              hipStream_t stream) {
    const float* pred  = (const float*)d_in[0];
    const float* targ  = (const float*)d_in[1];
    const int*   faces = (const int*)d_in[2];
    float*       out   = (float*)d_out;
    _Float16*    fd    = (_Float16*)d_ws;   // 2 arrays x 79872 faces x 64 B = 10.2 MB

    face_quant_kernel<<<(NTOT + 255) / 256, 256, 0, stream>>>(
        pred, targ, faces, fd, out);

    dim3 grid((NPAN / 2) * SPLITS, 1, BATCH);   // 78*13 = 1014 x 1 x 4 = 4056 blocks
    pair_sum_kernel<<<grid, 256, 0, stream>>>(fd, out);
}